// Round 2
// 857.311 us; speedup vs baseline: 1.3955x; 1.3955x over previous
//
#include <hip/hip_runtime.h>
#include <hip/hip_bf16.h>

typedef short bf16x8 __attribute__((ext_vector_type(8)));
typedef float f32x4  __attribute__((ext_vector_type(4)));
typedef int   i32x4  __attribute__((ext_vector_type(4)));

#define N_PTS  1000000
#define K_VOL  27
#define C_IN   64
#define C_OUT  64
#define ROWS_PER_BLOCK 256           // 4 waves x 4 row-tiles x 16 rows
#define NIDX   (ROWS_PER_BLOCK * K_VOL)   // 6912 ints = 27648 B LDS

static __device__ __forceinline__ short f2bf(float x) {
    __hip_bfloat16 h = __float2bfloat16(x);
    return *(short*)&h;
}

// ---------------------------------------------------------------------------
// Convert features fp32 [N][64] -> bf16 [N][64] in ws. 8 elems per thread.
// ---------------------------------------------------------------------------
__global__ __launch_bounds__(256) void cvt_feat(const float* __restrict__ f,
                                                __hip_bfloat16* __restrict__ o,
                                                int n8) {
    int id = blockIdx.x * 256 + threadIdx.x;
    if (id >= n8) return;
    const float4* src = (const float4*)f;
    float4 a = src[id * 2 + 0];
    float4 b = src[id * 2 + 1];
    bf16x8 v;
    v[0] = f2bf(a.x); v[1] = f2bf(a.y); v[2] = f2bf(a.z); v[3] = f2bf(a.w);
    v[4] = f2bf(b.x); v[5] = f2bf(b.y); v[6] = f2bf(b.z); v[7] = f2bf(b.w);
    ((bf16x8*)o)[id] = v;
}

// ---------------------------------------------------------------------------
// Repack W fp32 [27][64][64] (k, ci, co) -> bf16 MFMA-B-fragment order.
// chunk id = k*512 + s*256 + t*64 + lane  (s = k-step 0/1, t = col-tile 0..3)
// elem j of chunk = W[k][s*32 + (lane>>4)*8 + j][t*16 + (lane&15)]
// ---------------------------------------------------------------------------
__global__ void repack_w(const float* __restrict__ W,
                         __hip_bfloat16* __restrict__ outw) {
    int id = blockIdx.x * 256 + threadIdx.x;          // 0 .. 27*2*4*64-1
    if (id >= K_VOL * 2 * 4 * 64) return;
    int lane = id & 63;
    int t    = (id >> 6) & 3;
    int s    = (id >> 8) & 1;
    int k    = id >> 9;
    int ci0  = s * 32 + (lane >> 4) * 8;
    int co   = t * 16 + (lane & 15);
    const float* src = W + (k * C_IN + ci0) * C_OUT + co;
    bf16x8 v;
#pragma unroll
    for (int j = 0; j < 8; ++j) v[j] = f2bf(src[j * C_OUT]);
    ((bf16x8*)outw)[id] = v;
}

// ---------------------------------------------------------------------------
// Main gather-GEMM. Block = 256 rows x 64 cols. 4 waves; each wave owns
// 64 rows as 4 row-tiles of 16, with 4x4 mfma_f32_16x16x32_bf16 accumulators.
// Per k-iter per wave: 8 gather loads + 8 B loads feed 32 MFMAs
// (0.5 VMEM/MFMA vs 1.25 in the 1-tile version; 8 gathers in flight).
// ---------------------------------------------------------------------------
__global__ __launch_bounds__(256) void sconv_kernel(
    const __hip_bfloat16* __restrict__ feat,
    const int* __restrict__ kmap,
    const int* __restrict__ kmask,
    const __hip_bfloat16* __restrict__ wfrag,
    float* __restrict__ out) {

    __shared__ int s_idx[NIDX];

    const int tid = threadIdx.x;
    const int rb  = blockIdx.x * ROWS_PER_BLOCK;
    const size_t base27 = (size_t)rb * K_VOL;
    const bool full = (rb + ROWS_PER_BLOCK <= N_PTS);

    // Stage pre-masked indices: s_idx[row_local*27 + k] = mask ? idx : -1
    if (full) {
        const i32x4* kmap4  = (const i32x4*)(kmap  + base27);
        const i32x4* kmask4 = (const i32x4*)(kmask + base27);
        i32x4* s4 = (i32x4*)s_idx;
        for (int i = tid; i < NIDX / 4; i += 256) {
            i32x4 m = kmask4[i];
            i32x4 v = kmap4[i];
            i32x4 r;
            r[0] = m[0] ? v[0] : -1;
            r[1] = m[1] ? v[1] : -1;
            r[2] = m[2] ? v[2] : -1;
            r[3] = m[3] ? v[3] : -1;
            s4[i] = r;
        }
    } else {
        // tail block: scalar guarded path (simple, rarely taken)
        const int nvalid = (N_PTS - rb) * K_VOL;
        for (int i = tid; i < NIDX; i += 256) {
            int r = -1;
            if (i < nvalid) {
                int m = kmask[base27 + i];
                r = m ? kmap[base27 + i] : -1;
            }
            s_idx[i] = r;
        }
    }
    __syncthreads();

    const int lane = tid & 63;
    const int wave = tid >> 6;
    const int mrow = lane & 15;     // A row within a 16-row tile / C col
    const int g    = lane >> 4;     // A k-quad: ci slice g*8..g*8+7

    const bf16x8* __restrict__ f8 = (const bf16x8*)feat;
    const bf16x8* w8 = (const bf16x8*)wfrag + lane;

    f32x4 acc[4][4];
#pragma unroll
    for (int t = 0; t < 4; ++t)
#pragma unroll
        for (int c = 0; c < 4; ++c) acc[t][c] = (f32x4){0.f, 0.f, 0.f, 0.f};

    // lane's index pointer: row_local = wave*64 + t*16 + mrow
    const int* sidx = s_idx + (wave * 64 + mrow) * K_VOL;

#pragma unroll 1
    for (int k = 0; k < K_VOL; ++k) {
        // --- issue all 8 gathers first (4 row-tiles x 2 halves) ---
        bf16x8 a0[4], a1[4];
#pragma unroll
        for (int t = 0; t < 4; ++t) {
            int idx = sidx[t * 16 * K_VOL + k];
            a0[t] = (bf16x8){0, 0, 0, 0, 0, 0, 0, 0};
            a1[t] = (bf16x8){0, 0, 0, 0, 0, 0, 0, 0};
            if (idx >= 0) {
                const bf16x8* fr = f8 + (size_t)idx * 8 + g;
                a0[t] = fr[0];   // ci = g*8 .. g*8+7        (k-step s=0)
                a1[t] = fr[4];   // ci = 32 + g*8 .. +7      (k-step s=1)
            }
        }
        // --- B fragments (L1-resident, shared across waves/blocks) ---
        const bf16x8* wb = w8 + (size_t)k * 512;
        bf16x8 b00 = wb[0 * 64];
        bf16x8 b01 = wb[1 * 64];
        bf16x8 b02 = wb[2 * 64];
        bf16x8 b03 = wb[3 * 64];
        bf16x8 b10 = wb[4 * 64];
        bf16x8 b11 = wb[5 * 64];
        bf16x8 b12 = wb[6 * 64];
        bf16x8 b13 = wb[7 * 64];

#pragma unroll
        for (int t = 0; t < 4; ++t) {
            acc[t][0] = __builtin_amdgcn_mfma_f32_16x16x32_bf16(a0[t], b00, acc[t][0], 0, 0, 0);
            acc[t][1] = __builtin_amdgcn_mfma_f32_16x16x32_bf16(a0[t], b01, acc[t][1], 0, 0, 0);
            acc[t][2] = __builtin_amdgcn_mfma_f32_16x16x32_bf16(a0[t], b02, acc[t][2], 0, 0, 0);
            acc[t][3] = __builtin_amdgcn_mfma_f32_16x16x32_bf16(a0[t], b03, acc[t][3], 0, 0, 0);
            acc[t][0] = __builtin_amdgcn_mfma_f32_16x16x32_bf16(a1[t], b10, acc[t][0], 0, 0, 0);
            acc[t][1] = __builtin_amdgcn_mfma_f32_16x16x32_bf16(a1[t], b11, acc[t][1], 0, 0, 0);
            acc[t][2] = __builtin_amdgcn_mfma_f32_16x16x32_bf16(a1[t], b12, acc[t][2], 0, 0, 0);
            acc[t][3] = __builtin_amdgcn_mfma_f32_16x16x32_bf16(a1[t], b13, acc[t][3], 0, 0, 0);
        }
    }

    // Epilogue. C/D layout (verified m89/m91): col = lane&15, row = (lane>>4)*4 + reg
    const int orow0 = rb + wave * 64 + g * 4;
#pragma unroll
    for (int t = 0; t < 4; ++t) {
        const int rowb = orow0 + t * 16;
#pragma unroll
        for (int j = 0; j < 4; ++j) {
            const int row = rowb + j;
            if (full || row < N_PTS) {
                size_t r = (size_t)row * C_OUT + mrow;
                out[r +  0] = acc[t][0][j];
                out[r + 16] = acc[t][1][j];
                out[r + 32] = acc[t][2][j];
                out[r + 48] = acc[t][3][j];
            }
        }
    }
}

extern "C" void kernel_launch(void* const* d_in, const int* in_sizes, int n_in,
                              void* d_out, int out_size, void* d_ws, size_t ws_size,
                              hipStream_t stream) {
    const float* feat32 = (const float*)d_in[0];   // [1e6][64] fp32
    const float* W      = (const float*)d_in[1];   // [27][64][64] fp32
    const int*   kmap   = (const int*)d_in[2];     // [1e6][27] int32
    const int*   kmask  = (const int*)d_in[3];     // [1e6][27] int32
    float*       out    = (float*)d_out;           // [1e6][64] fp32

    // ws layout: [0, 128MB) bf16 features; then 221184 B repacked bf16 W
    __hip_bfloat16* featbf = (__hip_bfloat16*)d_ws;
    __hip_bfloat16* wfrag  = (__hip_bfloat16*)((char*)d_ws +
                              (size_t)N_PTS * C_IN * sizeof(__hip_bfloat16));

    const int n8 = N_PTS * C_IN / 8;               // 8e6 chunks of 8 elems
    cvt_feat<<<(n8 + 255) / 256, 256, 0, stream>>>(feat32, featbf, n8);

    const int repack_threads = K_VOL * 2 * 4 * 64; // 13824
    repack_w<<<(repack_threads + 255) / 256, 256, 0, stream>>>(W, wfrag);

    const int nblocks = (N_PTS + ROWS_PER_BLOCK - 1) / ROWS_PER_BLOCK; // 3907
    sconv_kernel<<<nblocks, 256, 0, stream>>>(featbf, kmap, kmask, wfrag, out);
}